// Round 10
// baseline (322.742 us; speedup 1.0000x reference)
//
#include <hip/hip_runtime.h>
#include <math.h>

// ---------- types ----------
typedef short short8_t __attribute__((ext_vector_type(8)));
typedef __bf16 bf16x8_t __attribute__((ext_vector_type(8)));
typedef float f32x4_t __attribute__((ext_vector_type(4)));

__device__ __forceinline__ float bf2f(unsigned short u) {
  unsigned v = ((unsigned)u) << 16;
  return __builtin_bit_cast(float, v);
}
__device__ __forceinline__ unsigned short f2bf(float f) {
  unsigned x = __builtin_bit_cast(unsigned, f);
  x += 0x7fffu + ((x >> 16) & 1u);
  return (unsigned short)(x >> 16);
}

// ---------- constants ----------
#define NA 8192
#define NB 8192
#define NBATCH 4
#define DIM 256
#define NPTS (NBATCH * NA)  // 32768
#define NCELL 2048          // 4 batches x 8x8x8 cells (cell edge 16)
#define SUBL 8              // lanes cooperating per a-point in topk_bins

// Branchless sorted top-8 insert: k[0..7] ascending, ~15 VALU ops.
__device__ __forceinline__ void kins(unsigned k[8], unsigned x) {
  unsigned c = x < k[7] ? x : k[7];
#pragma unroll
  for (int i = 6; i >= 0; i--) {
    unsigned hi = k[i] > c ? k[i] : c;
    c = k[i] < c ? k[i] : c;
    k[i + 1] = hi;
  }
  k[0] = c;
}

// ---------- prep: weights to bf16 (+ zero the binning counters) ----------
__global__ __launch_bounds__(256) void prep_weights(
    const float* __restrict__ w1, const float* __restrict__ w2,
    unsigned short* __restrict__ Wdiff, unsigned short* __restrict__ Wb,
    unsigned short* __restrict__ W2b, unsigned* __restrict__ bcnt,
    unsigned* __restrict__ acnt, unsigned* __restrict__ failcnt) {
  int d = blockIdx.x, t = threadIdx.x;
  float wa = w1[d * 512 + t];
  float wb = w1[d * 512 + 256 + t];
  Wdiff[d * 256 + t] = f2bf(wa - wb);
  Wb[d * 256 + t] = f2bf(wb);
  W2b[d * 256 + t] = f2bf(w2[d * 256 + t]);
  if (d < 8) {  // fold zero_counts: 8*256 = 2048 = NCELL
    int i = d * 256 + t;
    bcnt[i] = 0;
    acnt[i] = 0;
    if (i == 0) *failcnt = 0;
  }
}

// ---------- binning: pack coords (//16, 7b each) + histogram cells ----------
// One launch covers both point sets: blocks [0,128) -> b, [128,256) -> a.
__global__ __launch_bounds__(256) void pack_count_ab(
    const int* __restrict__ coords_b, const int* __restrict__ coords_a,
    unsigned* __restrict__ bpk, unsigned* __restrict__ apk,
    unsigned* __restrict__ bcnt, unsigned* __restrict__ acnt) {
  int gi = blockIdx.x * 256 + threadIdx.x;  // [0, 2*NPTS)
  const int isA = gi >= NPTS;
  const int i = gi & (NPTS - 1);
  const int* __restrict__ coords = isA ? coords_a : coords_b;
  unsigned* __restrict__ pk = isA ? apk : bpk;
  unsigned* __restrict__ cnt = isA ? acnt : bcnt;
  int x = (coords[(size_t)i * 3 + 0] >> 4) & 127;
  int y = (coords[(size_t)i * 3 + 1] >> 4) & 127;
  int z = (coords[(size_t)i * 3 + 2] >> 4) & 127;
  pk[i] = (unsigned)(x | (y << 7) | (z << 14));
  int cid = ((i >> 13) << 9) | ((x >> 4) << 6) | ((y >> 4) << 3) | (z >> 4);
  atomicAdd(cnt + cid, 1u);
}

// ---------- binning: exclusive scan of both 2048-entry tables ----------
__global__ __launch_bounds__(256) void scan_cells(
    const unsigned* __restrict__ bcnt, const unsigned* __restrict__ acnt,
    unsigned* __restrict__ boff, unsigned* __restrict__ aoff,
    unsigned* __restrict__ bcur, unsigned* __restrict__ acur) {
  __shared__ unsigned p[256];
  const int t = threadIdx.x;
  for (int tab = 0; tab < 2; tab++) {
    const unsigned* cnt = tab ? acnt : bcnt;
    unsigned* off = tab ? aoff : boff;
    unsigned* cur = tab ? acur : bcur;
    unsigned loc[8], sum = 0;
#pragma unroll
    for (int k = 0; k < 8; k++) { loc[k] = sum; sum += cnt[t * 8 + k]; }
    p[t] = sum;
    __syncthreads();
    for (int d = 1; d < 256; d <<= 1) {
      unsigned v = (t >= d) ? p[t - d] : 0u;
      __syncthreads();
      p[t] += v;
      __syncthreads();
    }
    unsigned base = (t == 0) ? 0u : p[t - 1];
#pragma unroll
    for (int k = 0; k < 8; k++) {
      unsigned o = base + loc[k];
      off[t * 8 + k] = o;
      cur[t * 8 + k] = o;
    }
    if (t == 255) off[2048] = base + sum;
    __syncthreads();
  }
}

// ---------- binning: scatter points into cell-sorted {coord, idx} pairs ----------
__global__ __launch_bounds__(256) void scatter_ab(
    const unsigned* __restrict__ bpk, const unsigned* __restrict__ apk,
    unsigned* __restrict__ bcur, unsigned* __restrict__ acur,
    uint2* __restrict__ bout, uint2* __restrict__ aout) {
  int gi = blockIdx.x * 256 + threadIdx.x;  // [0, 2*NPTS)
  const int isA = gi >= NPTS;
  const int i = gi & (NPTS - 1);
  const unsigned* __restrict__ pk = isA ? apk : bpk;
  unsigned* __restrict__ cur = isA ? acur : bcur;
  uint2* __restrict__ out = isA ? aout : bout;
  unsigned v = pk[i];
  int cx = (v & 127) >> 4, cy = ((v >> 7) & 127) >> 4, cz = ((v >> 14) & 127) >> 4;
  int cid = ((i >> 13) << 9) | (cx << 6) | (cy << 3) | cz;
  unsigned pos = atomicAdd(cur + cid, 1u);
  out[pos] = make_uint2(v, (unsigned)(i & 8191));
}

// ---------- GEMM: one WAVE per 16x256 strip, per-wave LDS staging ----------
// Zero barriers (no compiler-forced vmcnt(0) drains; waves fully
// independent). A strip is staged COALESCED: lane l loads 16B at
// row*1KB + l*16B (1KB bursts), cvt f32->bf16, ds_write into a private
// LDS region; producer==consumer wave, so ordering is wave-local lgkmcnt,
// no __syncthreads. B fragments load directly from L2/L1-hot W (128KB;
// scatter tolerable there - r6 evidence).
// Round-8 lesson: per-lane strided A loads ran at 850 GB/s (16 scattered
// 64B transactions/load); coalescing is the fix.
// Round-9 lesson: the staged row is 256 bf16 wide -> row stride must be
// >=256. ASTRIDE=264 shorts (=528B: 16B-aligned for ds_read_b128, +8 pad
// breaks pow-2 banks). r9's LDT=72 overlapped rows -> absmax 11.8.
// F32IN=1: A is f32; copyout!=null streams the f32 A values to
// outp[:, 0:256] (the ME.cat copy) for free, also coalesced.
#define ASTRIDE 264
template <int F32IN>
__device__ __forceinline__ void gemm_strip(
    int strip, const void* __restrict__ Ain, const short* __restrict__ W,
    float* __restrict__ Cf, unsigned short* __restrict__ Cb,
    const float* __restrict__ bias, float bias_scale, int c_stride,
    int c_coloff, float* __restrict__ copyout, short* Asw) {
  const int lane = threadIdx.x & 63;
  const int r = lane & 15, g = lane >> 4;
  const int row0 = strip * 16;
  const float* Af = (const float*)Ain;
  const short* Ab = (const short*)Ain;
  if (F32IN) {
#pragma unroll
    for (int t = 0; t < 16; t++) {
      const float* s = Af + (size_t)(row0 + t) * 256 + lane * 4;
      float4 v = *(const float4*)s;
      ushort4 o;
      o.x = f2bf(v.x); o.y = f2bf(v.y); o.z = f2bf(v.z); o.w = f2bf(v.w);
      *(ushort4*)(Asw + t * ASTRIDE + lane * 4) = o;
      if (copyout)
        *(float4*)(copyout + (size_t)(row0 + t) * 512 + lane * 4) = v;
    }
  } else {
#pragma unroll
    for (int t = 0; t < 8; t++) {
      int row = 2 * t + (lane >> 5);
      int col = (lane & 31) * 8;
      short8_t v = *(const short8_t*)(Ab + (size_t)(row0 + row) * 256 + col);
      *(short8_t*)(Asw + row * ASTRIDE + col) = v;
    }
  }
  // fragments back from LDS (wave-local dependency, lgkmcnt only)
  bf16x8_t a[8];
#pragma unroll
  for (int k = 0; k < 8; k++)
    a[k] = __builtin_bit_cast(bf16x8_t,
        *(const short8_t*)(Asw + r * ASTRIDE + k * 32 + g * 8));
  const short* wb = W + (size_t)r * 256 + g * 8;
  f32x4_t acc[16];
#pragma unroll
  for (int j = 0; j < 16; j++) acc[j] = f32x4_t{0.f, 0.f, 0.f, 0.f};
#pragma unroll
  for (int j = 0; j < 16; j++) {
    bf16x8_t b[8];
#pragma unroll
    for (int k = 0; k < 8; k++)
      b[k] = __builtin_bit_cast(bf16x8_t,
          *(const short8_t*)(wb + (size_t)j * 16 * 256 + k * 32));
#pragma unroll
    for (int k = 0; k < 8; k++)
      acc[j] = __builtin_amdgcn_mfma_f32_16x16x32_bf16(a[k], b[k], acc[j],
                                                       0, 0, 0);
  }
  // epilogue: C/D layout col=lane&15, row=(lane>>4)*4+rr
#pragma unroll
  for (int j = 0; j < 16; j++) {
    float bv = bias ? bias[j * 16 + r] * bias_scale : 0.f;
#pragma unroll
    for (int rr = 0; rr < 4; rr++) {
      float v = acc[j][rr] + bv;
      size_t off =
          (size_t)(row0 + g * 4 + rr) * c_stride + c_coloff + j * 16 + r;
      if (Cf) Cf[off] = v;
      else Cb[off] = f2bf(v);
    }
  }
}

// Pa and Pb GEMMs are independent -> one launch; waves [0,2048) do Pa strips,
// [2048,4096) do Pb strips.
__global__ __launch_bounds__(256) void gemm_ab(
    const float* __restrict__ a_feats, const float* __restrict__ b_feats,
    const short* __restrict__ Wb16, const short* __restrict__ Wdiff,
    unsigned short* __restrict__ Pa, unsigned short* __restrict__ Pb,
    const float* __restrict__ b1, float* __restrict__ outp) {
  __shared__ __attribute__((aligned(16))) short As[4][16 * ASTRIDE];
  const int wv = threadIdx.x >> 6;
  const int wave = blockIdx.x * 4 + wv;
  const int ns = NPTS / 16;  // 2048
  const int isB = wave >= ns;
  const int strip = isB ? (wave - ns) : wave;
  const float* Af = isB ? b_feats : a_feats;
  const short* W = isB ? Wdiff : Wb16;
  unsigned short* P = isB ? Pb : Pa;
  const float* bias = isB ? nullptr : b1;
  float* copy = isB ? nullptr : outp;
  gemm_strip<1>(strip, (const void*)Af, W, nullptr, P, bias, 1.0f, 256, 0,
                copy, As[wv]);
}

// Final: out[:, :, 256:512] = H @ w2^T + 8*b2
__global__ __launch_bounds__(256) void gemm_h(
    const short* __restrict__ Hb, const short* __restrict__ W2b,
    float* __restrict__ outp, const float* __restrict__ b2) {
  __shared__ __attribute__((aligned(16))) short As[4][16 * ASTRIDE];
  const int wv = threadIdx.x >> 6;
  const int strip = blockIdx.x * 4 + wv;
  gemm_strip<0>(strip, (const void*)Hb, W2b, outp, nullptr, b2, 8.0f, 512,
                256, nullptr, As[wv]);
}

// ---------- primary top-k: SUBL lanes per cell-sorted a-point ----------
// Each lane scans every SUBL-th candidate of the 3x3x3 neighborhood
// (adjacent lanes hit adjacent uint2 -> coalesced), then an aligned
// shfl-XOR butterfly merges the SUBL disjoint top-8 sets exactly.
// Exact iff merged 8th-best d2 <= 288 (outside neighborhood => d2 >= 289);
// sentinel keys exceed that, so <8 candidates also routes to fallback.
__global__ __launch_bounds__(256) void topk_bins(
    const unsigned* __restrict__ boff, const uint2* __restrict__ bcj,
    const uint2* __restrict__ acj, int* __restrict__ idxb,
    float* __restrict__ dwb, unsigned* __restrict__ failcnt,
    unsigned* __restrict__ faillist) {
  const int tid = blockIdx.x * 256 + threadIdx.x;
  const int t = tid / SUBL;        // cell-sorted a index
  const int sub = tid & (SUBL - 1);
  const uint2 av = acj[t];
  const int batch = t >> 13;  // batches are contiguous in cell order
  const int ax = av.x & 127, ay = (av.x >> 7) & 127, az = (av.x >> 14) & 127;
  const int cx = ax >> 4, cy = ay >> 4, cz = az >> 4;
  const int xlo = max(cx - 1, 0), xhi = min(cx + 1, 7);
  const int ylo = max(cy - 1, 0), yhi = min(cy + 1, 7);
  const int zlo = max(cz - 1, 0), zhi1 = min(cz + 1, 7) + 1;
  unsigned k[8];
#pragma unroll
  for (int s = 0; s < 8; s++) k[s] = 0xFFFFFFF8u + s;
  for (int nx = xlo; nx <= xhi; nx++) {
    for (int ny = ylo; ny <= yhi; ny++) {
      const int cb = (batch << 9) | (nx << 6) | (ny << 3);
      const int gs = (int)boff[cb + zlo];
      const int ge = (int)boff[cb + zhi1];
      for (int i = gs + sub; i < ge; i += SUBL) {
        const uint2 b = bcj[i];
        const int dx = ax - (int)(b.x & 127);
        const int dy = ay - (int)((b.x >> 7) & 127);
        const int dz = az - (int)((b.x >> 14) & 127);
        const unsigned d2 = (unsigned)(__mul24(dx, dx) + __mul24(dy, dy) +
                                       __mul24(dz, dz));
        kins(k, (d2 << 13) | b.y);
      }
    }
  }
  const int lane = threadIdx.x & 63;
#pragma unroll
  for (int half = 1; half < SUBL; half <<= 1) {
    unsigned o[8];
#pragma unroll
    for (int s = 0; s < 8; s++)
      o[s] = (unsigned)__shfl((int)k[s], lane ^ half, 64);
#pragma unroll
    for (int s = 0; s < 8; s++) kins(k, o[s]);
  }
  if (sub == 0) {
    const int g = (batch << 13) | (int)av.y;
#pragma unroll
    for (int s = 0; s < 8; s++) {
      unsigned key = k[s];
      idxb[(size_t)g * 8 + s] = (int)(key & 8191u);
      float dist = sqrtf((float)(key >> 13)) * (1.0f / 128.0f);
      dwb[(size_t)g * 8 + s] = 0.5f - fminf(dist, 0.5f);
    }
    if (k[7] >= (289u << 13)) {
      unsigned fp = atomicAdd(failcnt, 1u);
      faillist[fp] = (unsigned)g;
    }
  }
}

// ---------- fallback: exact full scan, one BLOCK (256 threads) per failed a-point ----------
// 256 lanes stride the 8192 candidates (32 iters/lane), unrolled 8-deep for
// load overlap; exact merge: wave butterfly then 3x8 keys folded through LDS
// into wave 0's sorted top-8.
__global__ __launch_bounds__(256) void topk_fallback(
    const unsigned* __restrict__ failcnt, const unsigned* __restrict__ faillist,
    const uint2* __restrict__ bcj, const unsigned* __restrict__ apk,
    int* __restrict__ idxb, float* __restrict__ dwb) {
  __shared__ unsigned sk[4 * 8];
  const int tid = threadIdx.x;
  const int wv = tid >> 6, lane = tid & 63;
  const unsigned nf = *failcnt;
  for (unsigned fi = blockIdx.x; fi < nf; fi += gridDim.x) {
    const unsigned g = faillist[fi];
    const int batch = (int)(g >> 13);
    const unsigned av = apk[g];
    const int ax = av & 127, ay = (av >> 7) & 127, az = (av >> 14) & 127;
    const uint2* pb = bcj + ((size_t)batch << 13);
    unsigned k[8];
#pragma unroll
    for (int s = 0; s < 8; s++) k[s] = 0xFFFFFFF8u + s;
#pragma unroll 8
    for (int i = tid; i < NB; i += 256) {
      const uint2 b = pb[i];
      const int dx = ax - (int)(b.x & 127);
      const int dy = ay - (int)((b.x >> 7) & 127);
      const int dz = az - (int)((b.x >> 14) & 127);
      const unsigned d2 = (unsigned)(__mul24(dx, dx) + __mul24(dy, dy) +
                                     __mul24(dz, dz));
      kins(k, (d2 << 13) | b.y);
    }
    // exact merge of the 64 disjoint per-lane top-8 sets within each wave
#pragma unroll
    for (int half = 32; half >= 1; half >>= 1) {
      unsigned o[8];
#pragma unroll
      for (int s = 0; s < 8; s++)
        o[s] = (unsigned)__shfl((int)k[s], lane ^ half, 64);
#pragma unroll
      for (int s = 0; s < 8; s++) kins(k, o[s]);
    }
    // cross-wave merge: waves 1..3 publish their top-8, wave 0 folds them in
    if (lane == 0) {
#pragma unroll
      for (int s = 0; s < 8; s++) sk[wv * 8 + s] = k[s];
    }
    __syncthreads();
    if (tid == 0) {
#pragma unroll
      for (int w = 1; w < 4; w++)
#pragma unroll
        for (int s = 0; s < 8; s++) kins(k, sk[w * 8 + s]);
#pragma unroll
      for (int s = 0; s < 8; s++) {
        unsigned key = k[s];
        idxb[(size_t)g * 8 + s] = (int)(key & 8191u);
        float dist = sqrtf((float)(key >> 13)) * (1.0f / 128.0f);
        dwb[(size_t)g * 8 + s] = 0.5f - fminf(dist, 0.5f);
      }
    }
    __syncthreads();  // sk reused next fi iteration
  }
}

// ---------- fuse: hsum = sum_k relu(Pa + Pb[idx_k]) * dw_k ----------
// Processes a-points in CELL-SORTED order (via acj): adjacent waves handle
// spatially adjacent a-points whose 8-neighbor sets overlap heavily, so the
// gathered Pb rows hit L1/L2 instead of HBM. Output rows land at the original
// index g (512B contiguous per wave; row order scattered - fine for HBM).
__global__ __launch_bounds__(256) void fuse_kernel(
    const unsigned short* __restrict__ Pa, const unsigned short* __restrict__ Pb,
    const uint2* __restrict__ acj, const int* __restrict__ idxb,
    const float* __restrict__ dwb, unsigned short* __restrict__ H) {
  const int t = blockIdx.x * 4 + (threadIdx.x >> 6);  // cell-sorted index
  const int lane = threadIdx.x & 63;
  const int batch = t >> 13;
  const uint2 av = acj[t];
  const int g = (batch << 13) | (int)av.y;
  const size_t fo = (size_t)g * 256 + lane * 4;
  ushort4 pav = *(const ushort4*)(Pa + fo);
  const float pa0 = bf2f(pav.x), pa1 = bf2f(pav.y), pa2 = bf2f(pav.z),
              pa3 = bf2f(pav.w);
  float h0 = 0.f, h1 = 0.f, h2 = 0.f, h3 = 0.f;
  const size_t bbase = (size_t)(batch << 13) * 256;
#pragma unroll
  for (int k = 0; k < 8; k++) {
    const int j = idxb[(size_t)g * 8 + k];
    const float w = dwb[(size_t)g * 8 + k];
    const ushort4 pbv =
        *(const ushort4*)(Pb + bbase + (size_t)j * 256 + lane * 4);
    h0 += fmaxf(pa0 + bf2f(pbv.x), 0.f) * w;
    h1 += fmaxf(pa1 + bf2f(pbv.y), 0.f) * w;
    h2 += fmaxf(pa2 + bf2f(pbv.z), 0.f) * w;
    h3 += fmaxf(pa3 + bf2f(pbv.w), 0.f) * w;
  }
  ushort4 hv;
  hv.x = f2bf(h0); hv.y = f2bf(h1); hv.z = f2bf(h2); hv.w = f2bf(h3);
  *(ushort4*)(H + fo) = hv;
}

// ---------- launch ----------
extern "C" void kernel_launch(void* const* d_in, const int* in_sizes, int n_in,
                              void* d_out, int out_size, void* d_ws,
                              size_t ws_size, hipStream_t stream) {
  const float* a_feats = (const float*)d_in[0];
  const float* b_feats = (const float*)d_in[1];
  const int* coords_a = (const int*)d_in[2];
  const int* coords_b = (const int*)d_in[3];
  const float* w1 = (const float*)d_in[4];
  const float* b1 = (const float*)d_in[5];
  const float* w2 = (const float*)d_in[6];
  const float* b2 = (const float*)d_in[7];
  float* outp = (float*)d_out;

  char* p = (char*)d_ws;
  auto take = [&](size_t bytes) {
    char* r = p;
    p += (bytes + 255) & ~(size_t)255;
    return r;
  };
  unsigned short* Pa = (unsigned short*)take((size_t)NPTS * DIM * 2);
  unsigned short* Pb = (unsigned short*)take((size_t)NPTS * DIM * 2);
  unsigned short* Hb = (unsigned short*)take((size_t)NPTS * DIM * 2);
  int* idxb = (int*)take((size_t)NPTS * 8 * 4);
  float* dwb = (float*)take((size_t)NPTS * 8 * 4);
  unsigned* bpk = (unsigned*)take((size_t)NPTS * 4);
  unsigned* apk = (unsigned*)take((size_t)NPTS * 4);
  unsigned* bcnt = (unsigned*)take(NCELL * 4);
  unsigned* acnt = (unsigned*)take(NCELL * 4);
  unsigned* bcur = (unsigned*)take(NCELL * 4);
  unsigned* acur = (unsigned*)take(NCELL * 4);
  unsigned* boff = (unsigned*)take((NCELL + 1) * 4);
  unsigned* aoff = (unsigned*)take((NCELL + 1) * 4);
  uint2* bcj = (uint2*)take((size_t)NPTS * 8);
  uint2* acj = (uint2*)take((size_t)NPTS * 8);
  unsigned* failcnt = (unsigned*)take(256);
  unsigned* faillist = (unsigned*)take((size_t)NPTS * 4);
  unsigned short* Wdiff = (unsigned short*)take(256 * 256 * 2);
  unsigned short* Wb16 = (unsigned short*)take(256 * 256 * 2);
  unsigned short* W2b = (unsigned short*)take(256 * 256 * 2);

  prep_weights<<<256, 256, 0, stream>>>(w1, w2, Wdiff, Wb16, W2b, bcnt, acnt,
                                        failcnt);
  pack_count_ab<<<2 * NPTS / 256, 256, 0, stream>>>(coords_b, coords_a, bpk,
                                                    apk, bcnt, acnt);
  scan_cells<<<1, 256, 0, stream>>>(bcnt, acnt, boff, aoff, bcur, acur);
  scatter_ab<<<2 * NPTS / 256, 256, 0, stream>>>(bpk, apk, bcur, acur, bcj,
                                                 acj);

  // Pa = A @ Wb^T + b1 ; Pb = B @ Wdiff^T -- one launch, wave-per-strip
  gemm_ab<<<2 * NPTS / 16 / 4, 256, 0, stream>>>(a_feats, b_feats,
                                                 (const short*)Wb16,
                                                 (const short*)Wdiff, Pa, Pb,
                                                 b1, outp);

  topk_bins<<<NPTS * SUBL / 256, 256, 0, stream>>>(boff, bcj, acj, idxb, dwb,
                                                   failcnt, faillist);
  topk_fallback<<<256, 256, 0, stream>>>(failcnt, faillist, bcj, apk, idxb,
                                         dwb);

  fuse_kernel<<<NPTS / 4, 256, 0, stream>>>(Pa, Pb, acj, idxb, dwb, Hb);

  // out[:, :, 256:512] = H @ w2^T + 8*b2
  gemm_h<<<NPTS / 16 / 4, 256, 0, stream>>>((const short*)Hb,
                                            (const short*)W2b, outp, b2);
}

// Round 12
// 222.264 us; speedup vs baseline: 1.4521x; 1.4521x over previous
//
#include <hip/hip_runtime.h>
#include <math.h>

// ---------- types ----------
typedef short short8_t __attribute__((ext_vector_type(8)));
typedef __bf16 bf16x8_t __attribute__((ext_vector_type(8)));
typedef float f32x4_t __attribute__((ext_vector_type(4)));
typedef __attribute__((address_space(1))) const unsigned as1_u32;
typedef __attribute__((address_space(3))) unsigned as3_u32;

__device__ __forceinline__ float bf2f(unsigned short u) {
  unsigned v = ((unsigned)u) << 16;
  return __builtin_bit_cast(float, v);
}
__device__ __forceinline__ unsigned short f2bf(float f) {
  unsigned x = __builtin_bit_cast(unsigned, f);
  x += 0x7fffu + ((x >> 16) & 1u);
  return (unsigned short)(x >> 16);
}

// ---------- constants ----------
#define NA 8192
#define NB 8192
#define NBATCH 4
#define DIM 256
#define NPTS (NBATCH * NA)  // 32768
#define NCELL 2048          // 4 batches x 8x8x8 cells (cell edge 16)
#define SUBL 8              // lanes cooperating per a-point in topk_bins
#define LDT 72              // padded row stride (shorts) for LDS tiles
#define WSLAB (256 * LDT)   // one k0-slab of pre-padded W: 18432 shorts = 36 KB

// Branchless sorted top-8 insert: k[0..7] ascending, ~15 VALU ops.
__device__ __forceinline__ void kins(unsigned k[8], unsigned x) {
  unsigned c = x < k[7] ? x : k[7];
#pragma unroll
  for (int i = 6; i >= 0; i--) {
    unsigned hi = k[i] > c ? k[i] : c;
    c = k[i] < c ? k[i] : c;
    k[i + 1] = hi;
  }
  k[0] = c;
}

// ---------- prep: weights to bf16, PRE-PADDED k0-slab layout ----------
// W stored as 4 slabs of [256 rows][72] shorts (cols 64..71 unwritten pad):
// slab s, row r holds W[r][64s..64s+63]. This makes each GEMM B-tile a
// byte-exact LINEAR 36KB global region so global_load_lds can stage it
// directly (linear dest requirement) while keeping the LDT=72 pad.
__global__ __launch_bounds__(256) void prep_weights(
    const float* __restrict__ w1, const float* __restrict__ w2,
    unsigned short* __restrict__ Wdiff, unsigned short* __restrict__ Wb,
    unsigned short* __restrict__ W2b, unsigned* __restrict__ bcnt,
    unsigned* __restrict__ acnt, unsigned* __restrict__ failcnt) {
  int d = blockIdx.x, t = threadIdx.x;  // d = W row, t = W col
  float wa = w1[d * 512 + t];
  float wb = w1[d * 512 + 256 + t];
  const int idx = (t >> 6) * WSLAB + d * LDT + (t & 63);
  Wdiff[idx] = f2bf(wa - wb);
  Wb[idx] = f2bf(wb);
  W2b[idx] = f2bf(w2[d * 256 + t]);
  if (d < 8) {  // fold zero_counts: 8*256 = 2048 = NCELL
    int i = d * 256 + t;
    bcnt[i] = 0;
    acnt[i] = 0;
    if (i == 0) *failcnt = 0;
  }
}

// ---------- binning: pack coords (//16, 7b each) + histogram cells ----------
__global__ __launch_bounds__(256) void pack_count_ab(
    const int* __restrict__ coords_b, const int* __restrict__ coords_a,
    unsigned* __restrict__ bpk, unsigned* __restrict__ apk,
    unsigned* __restrict__ bcnt, unsigned* __restrict__ acnt) {
  int gi = blockIdx.x * 256 + threadIdx.x;  // [0, 2*NPTS)
  const int isA = gi >= NPTS;
  const int i = gi & (NPTS - 1);
  const int* __restrict__ coords = isA ? coords_a : coords_b;
  unsigned* __restrict__ pk = isA ? apk : bpk;
  unsigned* __restrict__ cnt = isA ? acnt : bcnt;
  int x = (coords[(size_t)i * 3 + 0] >> 4) & 127;
  int y = (coords[(size_t)i * 3 + 1] >> 4) & 127;
  int z = (coords[(size_t)i * 3 + 2] >> 4) & 127;
  pk[i] = (unsigned)(x | (y << 7) | (z << 14));
  int cid = ((i >> 13) << 9) | ((x >> 4) << 6) | ((y >> 4) << 3) | (z >> 4);
  atomicAdd(cnt + cid, 1u);
}

// ---------- binning: exclusive scan of both 2048-entry tables ----------
__global__ __launch_bounds__(256) void scan_cells(
    const unsigned* __restrict__ bcnt, const unsigned* __restrict__ acnt,
    unsigned* __restrict__ boff, unsigned* __restrict__ aoff,
    unsigned* __restrict__ bcur, unsigned* __restrict__ acur) {
  __shared__ unsigned p[256];
  const int t = threadIdx.x;
  for (int tab = 0; tab < 2; tab++) {
    const unsigned* cnt = tab ? acnt : bcnt;
    unsigned* off = tab ? aoff : boff;
    unsigned* cur = tab ? acur : bcur;
    unsigned loc[8], sum = 0;
#pragma unroll
    for (int k = 0; k < 8; k++) { loc[k] = sum; sum += cnt[t * 8 + k]; }
    p[t] = sum;
    __syncthreads();
    for (int d = 1; d < 256; d <<= 1) {
      unsigned v = (t >= d) ? p[t - d] : 0u;
      __syncthreads();
      p[t] += v;
      __syncthreads();
    }
    unsigned base = (t == 0) ? 0u : p[t - 1];
#pragma unroll
    for (int k = 0; k < 8; k++) {
      unsigned o = base + loc[k];
      off[t * 8 + k] = o;
      cur[t * 8 + k] = o;
    }
    if (t == 255) off[2048] = base + sum;
    __syncthreads();
  }
}

// ---------- binning: scatter points into cell-sorted {coord, idx} pairs ----------
__global__ __launch_bounds__(256) void scatter_ab(
    const unsigned* __restrict__ bpk, const unsigned* __restrict__ apk,
    unsigned* __restrict__ bcur, unsigned* __restrict__ acur,
    uint2* __restrict__ bout, uint2* __restrict__ aout) {
  int gi = blockIdx.x * 256 + threadIdx.x;  // [0, 2*NPTS)
  const int isA = gi >= NPTS;
  const int i = gi & (NPTS - 1);
  const unsigned* __restrict__ pk = isA ? apk : bpk;
  unsigned* __restrict__ cur = isA ? acur : bcur;
  uint2* __restrict__ out = isA ? aout : bout;
  unsigned v = pk[i];
  int cx = (v & 127) >> 4, cy = ((v >> 7) & 127) >> 4, cz = ((v >> 14) & 127) >> 4;
  int cid = ((i >> 13) << 9) | (cx << 6) | (cy << 3) | cz;
  unsigned pos = atomicAdd(cur + cid, 1u);
  out[pos] = make_uint2(v, (unsigned)(i & 8191));
}

// ---------- GEMM body: C[64,256] tile = A[64,256] x W[256,256]^T ----------
// 64-row tile, 256 threads (4 waves, wave w owns cols w*64..w*64+64),
// 46 KB LDS -> 3 blocks/CU (best-known structure: r4 submission, 227us).
// NEW: B tile staged with global_load_lds width=16 (9 lds-direct loads per
// thread from the pre-padded W slab; no VGPR round-trip, no ds_writes) --
// the m97-ladder lever. Issued BEFORE A staging so they fly under A's
// load+cvt work. Evidence r8/r10: per-wave direct-from-L2 B reads (no LDS)
// run 2.5x slower; B must be LDS-staged, and this is the cheapest staging.
// F32IN=1: A is f32, cvt during staging; copyout!=null streams the f32 A
// values to outp[:, 0:256] (the ME.cat copy) for free.
template <int F32IN>
__device__ __forceinline__ void gemm64_body(
    int rowblk, const void* __restrict__ Ain, const short* __restrict__ W,
    float* __restrict__ Cf, unsigned short* __restrict__ Cb,
    const float* __restrict__ bias, float bias_scale, int c_stride,
    int c_coloff, float* __restrict__ copyout, short* As, short* Bs) {
  const int tid = threadIdx.x;
  const int row0 = rowblk * 64;
  const int w = tid >> 6, lane = tid & 63;
  const int wn = w * 64;
  f32x4_t acc[4][4] = {};
  for (int k0 = 0; k0 < 256; k0 += 64) {
    // B tile: linear 36KB copy of slab (k0>>6) via lds-direct loads
    {
      const short* wslab = W + (size_t)(k0 >> 6) * WSLAB;
#pragma unroll
      for (int it = 0; it < 9; it++) {
        const unsigned* g = (const unsigned*)(wslab + it * 2048 + tid * 8);
        unsigned* l = (unsigned*)(Bs + it * 2048 + tid * 8);
        __builtin_amdgcn_global_load_lds((as1_u32*)g, (as3_u32*)l, 16, 0, 0);
      }
    }
    // A tile: reg-staged (f32->bf16 cvt path needs the round-trip)
    if (F32IN) {
      const float* Af = (const float*)Ain;
#pragma unroll
      for (int i = 0; i < 2; i++) {
        int c = tid + 256 * i;  // 0..511 -> 64 rows x 8 chunks
        int r = c >> 3, kc = (c & 7) * 8;
        const float* src = Af + (size_t)(row0 + r) * 256 + k0 + kc;
        float4 v0 = *(const float4*)src;
        float4 v1 = *(const float4*)(src + 4);
        short8_t vb;
        vb[0] = (short)f2bf(v0.x); vb[1] = (short)f2bf(v0.y);
        vb[2] = (short)f2bf(v0.z); vb[3] = (short)f2bf(v0.w);
        vb[4] = (short)f2bf(v1.x); vb[5] = (short)f2bf(v1.y);
        vb[6] = (short)f2bf(v1.z); vb[7] = (short)f2bf(v1.w);
        *(short8_t*)(As + r * LDT + kc) = vb;
        if (copyout) {
          float4* dst = (float4*)(copyout + (size_t)(row0 + r) * 512 + k0 + kc);
          dst[0] = v0;
          dst[1] = v1;
        }
      }
    } else {
      const short* Ab = (const short*)Ain;
#pragma unroll
      for (int i = 0; i < 2; i++) {
        int c = tid + 256 * i;
        int r = c >> 3, kc = (c & 7) * 8;
        *(short8_t*)(As + r * LDT + kc) =
            *(const short8_t*)(Ab + (size_t)(row0 + r) * 256 + k0 + kc);
      }
    }
    __syncthreads();
#pragma unroll
    for (int kk = 0; kk < 64; kk += 32) {
      const int kof = kk + (lane >> 4) * 8;
      bf16x8_t af[4], bfr[4];
#pragma unroll
      for (int i = 0; i < 4; i++) {
        af[i] = __builtin_bit_cast(bf16x8_t,
            *(const short8_t*)(As + (i * 16 + (lane & 15)) * LDT + kof));
        bfr[i] = __builtin_bit_cast(bf16x8_t,
            *(const short8_t*)(Bs + (wn + i * 16 + (lane & 15)) * LDT + kof));
      }
#pragma unroll
      for (int i = 0; i < 4; i++)
#pragma unroll
        for (int j = 0; j < 4; j++)
          acc[i][j] = __builtin_amdgcn_mfma_f32_16x16x32_bf16(
              af[i], bfr[j], acc[i][j], 0, 0, 0);
    }
    __syncthreads();
  }
#pragma unroll
  for (int i = 0; i < 4; i++) {
    int row = row0 + i * 16 + ((lane >> 4) * 4);
#pragma unroll
    for (int j = 0; j < 4; j++) {
      int col = wn + j * 16 + (lane & 15);
      float bv = bias ? bias[col] * bias_scale : 0.f;
#pragma unroll
      for (int r = 0; r < 4; r++) {
        float v = acc[i][j][r] + bv;
        size_t off = (size_t)(row + r) * c_stride + c_coloff + col;
        if (Cf) Cf[off] = v;
        else Cb[off] = f2bf(v);
      }
    }
  }
}

// Pa and Pb GEMMs are independent -> one launch, blocks [0,512) do Pa rows,
// [512,1024) do Pb rows. 3 blocks/CU co-resident hides staging latency.
__global__ __launch_bounds__(256, 3) void gemm_ab(
    const float* __restrict__ a_feats, const float* __restrict__ b_feats,
    const short* __restrict__ Wb16, const short* __restrict__ Wdiff,
    unsigned short* __restrict__ Pa, unsigned short* __restrict__ Pb,
    const float* __restrict__ b1, float* __restrict__ outp) {
  __shared__ __attribute__((aligned(16))) short As[64 * LDT];
  __shared__ __attribute__((aligned(16))) short Bs[256 * LDT];
  const int nb = NPTS / 64;  // 512
  const int isB = blockIdx.x >= nb;
  const int rowblk = isB ? (blockIdx.x - nb) : blockIdx.x;
  const float* Af = isB ? b_feats : a_feats;
  const short* W = isB ? Wdiff : Wb16;
  unsigned short* P = isB ? Pb : Pa;
  const float* bias = isB ? nullptr : b1;
  float* copy = isB ? nullptr : outp;
  gemm64_body<1>(rowblk, (const void*)Af, W, nullptr, P, bias, 1.0f, 256, 0,
                 copy, As, Bs);
}

// Final: out[:, :, 256:512] = H @ w2^T + 8*b2
__global__ __launch_bounds__(256, 3) void gemm_h(
    const short* __restrict__ Hb, const short* __restrict__ W2b,
    float* __restrict__ outp, const float* __restrict__ b2) {
  __shared__ __attribute__((aligned(16))) short As[64 * LDT];
  __shared__ __attribute__((aligned(16))) short Bs[256 * LDT];
  gemm64_body<0>(blockIdx.x, (const void*)Hb, W2b, outp, nullptr, b2, 8.0f,
                 512, 256, nullptr, As, Bs);
}

// ---------- primary top-k: SUBL lanes per cell-sorted a-point ----------
// Each lane scans every SUBL-th candidate of the 3x3x3 neighborhood
// (adjacent lanes hit adjacent uint2 -> coalesced), then an aligned
// shfl-XOR butterfly merges the SUBL disjoint top-8 sets exactly.
// Exact iff merged 8th-best d2 <= 288 (outside neighborhood => d2 >= 289);
// sentinel keys exceed that, so <8 candidates also routes to fallback.
__global__ __launch_bounds__(256) void topk_bins(
    const unsigned* __restrict__ boff, const uint2* __restrict__ bcj,
    const uint2* __restrict__ acj, int* __restrict__ idxb,
    float* __restrict__ dwb, unsigned* __restrict__ failcnt,
    unsigned* __restrict__ faillist) {
  const int tid = blockIdx.x * 256 + threadIdx.x;
  const int t = tid / SUBL;        // cell-sorted a index
  const int sub = tid & (SUBL - 1);
  const uint2 av = acj[t];
  const int batch = t >> 13;  // batches are contiguous in cell order
  const int ax = av.x & 127, ay = (av.x >> 7) & 127, az = (av.x >> 14) & 127;
  const int cx = ax >> 4, cy = ay >> 4, cz = az >> 4;
  const int xlo = max(cx - 1, 0), xhi = min(cx + 1, 7);
  const int ylo = max(cy - 1, 0), yhi = min(cy + 1, 7);
  const int zlo = max(cz - 1, 0), zhi1 = min(cz + 1, 7) + 1;
  unsigned k[8];
#pragma unroll
  for (int s = 0; s < 8; s++) k[s] = 0xFFFFFFF8u + s;
  for (int nx = xlo; nx <= xhi; nx++) {
    for (int ny = ylo; ny <= yhi; ny++) {
      const int cb = (batch << 9) | (nx << 6) | (ny << 3);
      const int gs = (int)boff[cb + zlo];
      const int ge = (int)boff[cb + zhi1];
      for (int i = gs + sub; i < ge; i += SUBL) {
        const uint2 b = bcj[i];
        const int dx = ax - (int)(b.x & 127);
        const int dy = ay - (int)((b.x >> 7) & 127);
        const int dz = az - (int)((b.x >> 14) & 127);
        const unsigned d2 = (unsigned)(__mul24(dx, dx) + __mul24(dy, dy) +
                                       __mul24(dz, dz));
        kins(k, (d2 << 13) | b.y);
      }
    }
  }
  const int lane = threadIdx.x & 63;
#pragma unroll
  for (int half = 1; half < SUBL; half <<= 1) {
    unsigned o[8];
#pragma unroll
    for (int s = 0; s < 8; s++)
      o[s] = (unsigned)__shfl((int)k[s], lane ^ half, 64);
#pragma unroll
    for (int s = 0; s < 8; s++) kins(k, o[s]);
  }
  if (sub == 0) {
    const int g = (batch << 13) | (int)av.y;
#pragma unroll
    for (int s = 0; s < 8; s++) {
      unsigned key = k[s];
      idxb[(size_t)g * 8 + s] = (int)(key & 8191u);
      float dist = sqrtf((float)(key >> 13)) * (1.0f / 128.0f);
      dwb[(size_t)g * 8 + s] = 0.5f - fminf(dist, 0.5f);
    }
    if (k[7] >= (289u << 13)) {
      unsigned fp = atomicAdd(failcnt, 1u);
      faillist[fp] = (unsigned)g;
    }
  }
}

// ---------- fallback: exact full scan, one BLOCK (256 threads) per failed a-point ----------
__global__ __launch_bounds__(256) void topk_fallback(
    const unsigned* __restrict__ failcnt, const unsigned* __restrict__ faillist,
    const uint2* __restrict__ bcj, const unsigned* __restrict__ apk,
    int* __restrict__ idxb, float* __restrict__ dwb) {
  __shared__ unsigned sk[4 * 8];
  const int tid = threadIdx.x;
  const int wv = tid >> 6, lane = tid & 63;
  const unsigned nf = *failcnt;
  for (unsigned fi = blockIdx.x; fi < nf; fi += gridDim.x) {
    const unsigned g = faillist[fi];
    const int batch = (int)(g >> 13);
    const unsigned av = apk[g];
    const int ax = av & 127, ay = (av >> 7) & 127, az = (av >> 14) & 127;
    const uint2* pb = bcj + ((size_t)batch << 13);
    unsigned k[8];
#pragma unroll
    for (int s = 0; s < 8; s++) k[s] = 0xFFFFFFF8u + s;
#pragma unroll 8
    for (int i = tid; i < NB; i += 256) {
      const uint2 b = pb[i];
      const int dx = ax - (int)(b.x & 127);
      const int dy = ay - (int)((b.x >> 7) & 127);
      const int dz = az - (int)((b.x >> 14) & 127);
      const unsigned d2 = (unsigned)(__mul24(dx, dx) + __mul24(dy, dy) +
                                     __mul24(dz, dz));
      kins(k, (d2 << 13) | b.y);
    }
#pragma unroll
    for (int half = 32; half >= 1; half >>= 1) {
      unsigned o[8];
#pragma unroll
      for (int s = 0; s < 8; s++)
        o[s] = (unsigned)__shfl((int)k[s], lane ^ half, 64);
#pragma unroll
      for (int s = 0; s < 8; s++) kins(k, o[s]);
    }
    if (lane == 0) {
#pragma unroll
      for (int s = 0; s < 8; s++) sk[wv * 8 + s] = k[s];
    }
    __syncthreads();
    if (tid == 0) {
#pragma unroll
      for (int w = 1; w < 4; w++)
#pragma unroll
        for (int s = 0; s < 8; s++) kins(k, sk[w * 8 + s]);
#pragma unroll
      for (int s = 0; s < 8; s++) {
        unsigned key = k[s];
        idxb[(size_t)g * 8 + s] = (int)(key & 8191u);
        float dist = sqrtf((float)(key >> 13)) * (1.0f / 128.0f);
        dwb[(size_t)g * 8 + s] = 0.5f - fminf(dist, 0.5f);
      }
    }
    __syncthreads();  // sk reused next fi iteration
  }
}

// ---------- fuse: hsum = sum_k relu(Pa + Pb[idx_k]) * dw_k ----------
// Processes a-points in CELL-SORTED order (via acj): adjacent waves handle
// spatially adjacent a-points whose 8-neighbor sets overlap heavily, so the
// gathered Pb rows hit L1/L2 instead of HBM.
__global__ __launch_bounds__(256) void fuse_kernel(
    const unsigned short* __restrict__ Pa, const unsigned short* __restrict__ Pb,
    const uint2* __restrict__ acj, const int* __restrict__ idxb,
    const float* __restrict__ dwb, unsigned short* __restrict__ H) {
  const int t = blockIdx.x * 4 + (threadIdx.x >> 6);  // cell-sorted index
  const int lane = threadIdx.x & 63;
  const int batch = t >> 13;
  const uint2 av = acj[t];
  const int g = (batch << 13) | (int)av.y;
  const size_t fo = (size_t)g * 256 + lane * 4;
  ushort4 pav = *(const ushort4*)(Pa + fo);
  const float pa0 = bf2f(pav.x), pa1 = bf2f(pav.y), pa2 = bf2f(pav.z),
              pa3 = bf2f(pav.w);
  float h0 = 0.f, h1 = 0.f, h2 = 0.f, h3 = 0.f;
  const size_t bbase = (size_t)(batch << 13) * 256;
#pragma unroll
  for (int k = 0; k < 8; k++) {
    const int j = idxb[(size_t)g * 8 + k];
    const float w = dwb[(size_t)g * 8 + k];
    const ushort4 pbv =
        *(const ushort4*)(Pb + bbase + (size_t)j * 256 + lane * 4);
    h0 += fmaxf(pa0 + bf2f(pbv.x), 0.f) * w;
    h1 += fmaxf(pa1 + bf2f(pbv.y), 0.f) * w;
    h2 += fmaxf(pa2 + bf2f(pbv.z), 0.f) * w;
    h3 += fmaxf(pa3 + bf2f(pbv.w), 0.f) * w;
  }
  ushort4 hv;
  hv.x = f2bf(h0); hv.y = f2bf(h1); hv.z = f2bf(h2); hv.w = f2bf(h3);
  *(ushort4*)(H + fo) = hv;
}

// ---------- launch ----------
extern "C" void kernel_launch(void* const* d_in, const int* in_sizes, int n_in,
                              void* d_out, int out_size, void* d_ws,
                              size_t ws_size, hipStream_t stream) {
  const float* a_feats = (const float*)d_in[0];
  const float* b_feats = (const float*)d_in[1];
  const int* coords_a = (const int*)d_in[2];
  const int* coords_b = (const int*)d_in[3];
  const float* w1 = (const float*)d_in[4];
  const float* b1 = (const float*)d_in[5];
  const float* w2 = (const float*)d_in[6];
  const float* b2 = (const float*)d_in[7];
  float* outp = (float*)d_out;

  char* p = (char*)d_ws;
  auto take = [&](size_t bytes) {
    char* r = p;
    p += (bytes + 255) & ~(size_t)255;
    return r;
  };
  unsigned short* Pa = (unsigned short*)take((size_t)NPTS * DIM * 2);
  unsigned short* Pb = (unsigned short*)take((size_t)NPTS * DIM * 2);
  unsigned short* Hb = (unsigned short*)take((size_t)NPTS * DIM * 2);
  int* idxb = (int*)take((size_t)NPTS * 8 * 4);
  float* dwb = (float*)take((size_t)NPTS * 8 * 4);
  unsigned* bpk = (unsigned*)take((size_t)NPTS * 4);
  unsigned* apk = (unsigned*)take((size_t)NPTS * 4);
  unsigned* bcnt = (unsigned*)take(NCELL * 4);
  unsigned* acnt = (unsigned*)take(NCELL * 4);
  unsigned* bcur = (unsigned*)take(NCELL * 4);
  unsigned* acur = (unsigned*)take(NCELL * 4);
  unsigned* boff = (unsigned*)take((NCELL + 1) * 4);
  unsigned* aoff = (unsigned*)take((NCELL + 1) * 4);
  uint2* bcj = (uint2*)take((size_t)NPTS * 8);
  uint2* acj = (uint2*)take((size_t)NPTS * 8);
  unsigned* failcnt = (unsigned*)take(256);
  unsigned* faillist = (unsigned*)take((size_t)NPTS * 4);
  unsigned short* Wdiff = (unsigned short*)take((size_t)4 * WSLAB * 2);
  unsigned short* Wb16 = (unsigned short*)take((size_t)4 * WSLAB * 2);
  unsigned short* W2b = (unsigned short*)take((size_t)4 * WSLAB * 2);

  prep_weights<<<256, 256, 0, stream>>>(w1, w2, Wdiff, Wb16, W2b, bcnt, acnt,
                                        failcnt);
  pack_count_ab<<<2 * NPTS / 256, 256, 0, stream>>>(coords_b, coords_a, bpk,
                                                    apk, bcnt, acnt);
  scan_cells<<<1, 256, 0, stream>>>(bcnt, acnt, boff, aoff, bcur, acur);
  scatter_ab<<<2 * NPTS / 256, 256, 0, stream>>>(bpk, apk, bcur, acur, bcj,
                                                 acj);

  // Pa = A @ Wb^T + b1 ; Pb = B @ Wdiff^T -- one launch, 1024 blocks
  gemm_ab<<<2 * NPTS / 64, 256, 0, stream>>>(a_feats, b_feats,
                                             (const short*)Wb16,
                                             (const short*)Wdiff, Pa, Pb, b1,
                                             outp);

  topk_bins<<<NPTS * SUBL / 256, 256, 0, stream>>>(boff, bcj, acj, idxb, dwb,
                                                   failcnt, faillist);
  topk_fallback<<<256, 256, 0, stream>>>(failcnt, faillist, bcj, apk, idxb,
                                         dwb);

  fuse_kernel<<<NPTS / 4, 256, 0, stream>>>(Pa, Pb, acj, idxb, dwb, Hb);

  // out[:, :, 256:512] = H @ w2^T + 8*b2
  gemm_h<<<NPTS / 64, 256, 0, stream>>>((const short*)Hb, (const short*)W2b,
                                        outp, b2);
}

// Round 13
// 216.350 us; speedup vs baseline: 1.4918x; 1.0273x over previous
//
#include <hip/hip_runtime.h>
#include <math.h>

// ---------- types ----------
typedef short short8_t __attribute__((ext_vector_type(8)));
typedef __bf16 bf16x8_t __attribute__((ext_vector_type(8)));
typedef float f32x4_t __attribute__((ext_vector_type(4)));
typedef __attribute__((address_space(1))) const unsigned as1_u32;
typedef __attribute__((address_space(3))) unsigned as3_u32;

__device__ __forceinline__ float bf2f(unsigned short u) {
  unsigned v = ((unsigned)u) << 16;
  return __builtin_bit_cast(float, v);
}
__device__ __forceinline__ unsigned short f2bf(float f) {
  unsigned x = __builtin_bit_cast(unsigned, f);
  x += 0x7fffu + ((x >> 16) & 1u);
  return (unsigned short)(x >> 16);
}

// ---------- constants ----------
#define NA 8192
#define NB 8192
#define NBATCH 4
#define DIM 256
#define NPTS (NBATCH * NA)  // 32768
#define NCELL 2048          // 4 batches x 8x8x8 cells (cell edge 16)
#define SUBL 8              // lanes cooperating per a-point in topk_bins
#define LDT 72              // padded row stride (shorts) for LDS tiles
#define WSLAB (256 * LDT)   // one k0-slab of pre-padded W: 18432 shorts = 36 KB

// Branchless sorted top-8 insert: k[0..7] ascending, ~15 VALU ops.
__device__ __forceinline__ void kins(unsigned k[8], unsigned x) {
  unsigned c = x < k[7] ? x : k[7];
#pragma unroll
  for (int i = 6; i >= 0; i--) {
    unsigned hi = k[i] > c ? k[i] : c;
    c = k[i] < c ? k[i] : c;
    k[i + 1] = hi;
  }
  k[0] = c;
}

// ---------- prep: weights to bf16, PRE-PADDED k0-slab layout ----------
// W stored as 4 slabs of [256 rows][72] shorts (cols 64..71 unwritten pad):
// slab s, row r holds W[r][64s..64s+63]. This makes each GEMM B-tile a
// byte-exact LINEAR 36KB global region so global_load_lds can stage it
// directly (linear dest requirement) while keeping the LDT=72 pad.
__global__ __launch_bounds__(256) void prep_weights(
    const float* __restrict__ w1, const float* __restrict__ w2,
    unsigned short* __restrict__ Wdiff, unsigned short* __restrict__ Wb,
    unsigned short* __restrict__ W2b, unsigned* __restrict__ bcnt,
    unsigned* __restrict__ acnt, unsigned* __restrict__ failcnt) {
  int d = blockIdx.x, t = threadIdx.x;  // d = W row, t = W col
  float wa = w1[d * 512 + t];
  float wb = w1[d * 512 + 256 + t];
  const int idx = (t >> 6) * WSLAB + d * LDT + (t & 63);
  Wdiff[idx] = f2bf(wa - wb);
  Wb[idx] = f2bf(wb);
  W2b[idx] = f2bf(w2[d * 256 + t]);
  if (d < 8) {  // fold zero_counts: 8*256 = 2048 = NCELL
    int i = d * 256 + t;
    bcnt[i] = 0;
    acnt[i] = 0;
    if (i == 0) *failcnt = 0;
  }
}

// ---------- binning: pack coords (//16, 7b each) + histogram cells ----------
__global__ __launch_bounds__(256) void pack_count_ab(
    const int* __restrict__ coords_b, const int* __restrict__ coords_a,
    unsigned* __restrict__ bpk, unsigned* __restrict__ apk,
    unsigned* __restrict__ bcnt, unsigned* __restrict__ acnt) {
  int gi = blockIdx.x * 256 + threadIdx.x;  // [0, 2*NPTS)
  const int isA = gi >= NPTS;
  const int i = gi & (NPTS - 1);
  const int* __restrict__ coords = isA ? coords_a : coords_b;
  unsigned* __restrict__ pk = isA ? apk : bpk;
  unsigned* __restrict__ cnt = isA ? acnt : bcnt;
  int x = (coords[(size_t)i * 3 + 0] >> 4) & 127;
  int y = (coords[(size_t)i * 3 + 1] >> 4) & 127;
  int z = (coords[(size_t)i * 3 + 2] >> 4) & 127;
  pk[i] = (unsigned)(x | (y << 7) | (z << 14));
  int cid = ((i >> 13) << 9) | ((x >> 4) << 6) | ((y >> 4) << 3) | (z >> 4);
  atomicAdd(cnt + cid, 1u);
}

// ---------- binning: exclusive scan of both 2048-entry tables ----------
__global__ __launch_bounds__(256) void scan_cells(
    const unsigned* __restrict__ bcnt, const unsigned* __restrict__ acnt,
    unsigned* __restrict__ boff, unsigned* __restrict__ aoff,
    unsigned* __restrict__ bcur, unsigned* __restrict__ acur) {
  __shared__ unsigned p[256];
  const int t = threadIdx.x;
  for (int tab = 0; tab < 2; tab++) {
    const unsigned* cnt = tab ? acnt : bcnt;
    unsigned* off = tab ? aoff : boff;
    unsigned* cur = tab ? acur : bcur;
    unsigned loc[8], sum = 0;
#pragma unroll
    for (int k = 0; k < 8; k++) { loc[k] = sum; sum += cnt[t * 8 + k]; }
    p[t] = sum;
    __syncthreads();
    for (int d = 1; d < 256; d <<= 1) {
      unsigned v = (t >= d) ? p[t - d] : 0u;
      __syncthreads();
      p[t] += v;
      __syncthreads();
    }
    unsigned base = (t == 0) ? 0u : p[t - 1];
#pragma unroll
    for (int k = 0; k < 8; k++) {
      unsigned o = base + loc[k];
      off[t * 8 + k] = o;
      cur[t * 8 + k] = o;
    }
    if (t == 255) off[2048] = base + sum;
    __syncthreads();
  }
}

// ---------- binning: scatter points into cell-sorted {coord, idx} pairs ----------
__global__ __launch_bounds__(256) void scatter_ab(
    const unsigned* __restrict__ bpk, const unsigned* __restrict__ apk,
    unsigned* __restrict__ bcur, unsigned* __restrict__ acur,
    uint2* __restrict__ bout, uint2* __restrict__ aout) {
  int gi = blockIdx.x * 256 + threadIdx.x;  // [0, 2*NPTS)
  const int isA = gi >= NPTS;
  const int i = gi & (NPTS - 1);
  const unsigned* __restrict__ pk = isA ? apk : bpk;
  unsigned* __restrict__ cur = isA ? acur : bcur;
  uint2* __restrict__ out = isA ? aout : bout;
  unsigned v = pk[i];
  int cx = (v & 127) >> 4, cy = ((v >> 7) & 127) >> 4, cz = ((v >> 14) & 127) >> 4;
  int cid = ((i >> 13) << 9) | (cx << 6) | (cy << 3) | cz;
  unsigned pos = atomicAdd(cur + cid, 1u);
  out[pos] = make_uint2(v, (unsigned)(i & 8191));
}

// ---------- GEMM body: C[64,256] tile = A[64,256] x W[256,256]^T ----------
// 64-row tile, 256 threads (4 waves, wave w owns cols w*64..w*64+64),
// 46 KB LDS -> 3 blocks/CU. B tile staged with global_load_lds width=16
// from the pre-padded W slab. F32IN=1: A is f32, cvt during staging;
// copyout!=null streams the f32 A values to outp[:, 0:256] for free.
template <int F32IN>
__device__ __forceinline__ void gemm64_body(
    int rowblk, const void* __restrict__ Ain, const short* __restrict__ W,
    float* __restrict__ Cf, unsigned short* __restrict__ Cb,
    const float* __restrict__ bias, float bias_scale, int c_stride,
    int c_coloff, float* __restrict__ copyout, short* As, short* Bs) {
  const int tid = threadIdx.x;
  const int row0 = rowblk * 64;
  const int w = tid >> 6, lane = tid & 63;
  const int wn = w * 64;
  f32x4_t acc[4][4] = {};
  for (int k0 = 0; k0 < 256; k0 += 64) {
    // B tile: linear 36KB copy of slab (k0>>6) via lds-direct loads
    {
      const short* wslab = W + (size_t)(k0 >> 6) * WSLAB;
#pragma unroll
      for (int it = 0; it < 9; it++) {
        const unsigned* g = (const unsigned*)(wslab + it * 2048 + tid * 8);
        unsigned* l = (unsigned*)(Bs + it * 2048 + tid * 8);
        __builtin_amdgcn_global_load_lds((as1_u32*)g, (as3_u32*)l, 16, 0, 0);
      }
    }
    // A tile: reg-staged (f32->bf16 cvt path needs the round-trip)
    if (F32IN) {
      const float* Af = (const float*)Ain;
#pragma unroll
      for (int i = 0; i < 2; i++) {
        int c = tid + 256 * i;  // 0..511 -> 64 rows x 8 chunks
        int r = c >> 3, kc = (c & 7) * 8;
        const float* src = Af + (size_t)(row0 + r) * 256 + k0 + kc;
        float4 v0 = *(const float4*)src;
        float4 v1 = *(const float4*)(src + 4);
        short8_t vb;
        vb[0] = (short)f2bf(v0.x); vb[1] = (short)f2bf(v0.y);
        vb[2] = (short)f2bf(v0.z); vb[3] = (short)f2bf(v0.w);
        vb[4] = (short)f2bf(v1.x); vb[5] = (short)f2bf(v1.y);
        vb[6] = (short)f2bf(v1.z); vb[7] = (short)f2bf(v1.w);
        *(short8_t*)(As + r * LDT + kc) = vb;
        if (copyout) {
          float4* dst = (float4*)(copyout + (size_t)(row0 + r) * 512 + k0 + kc);
          dst[0] = v0;
          dst[1] = v1;
        }
      }
    } else {
      const short* Ab = (const short*)Ain;
#pragma unroll
      for (int i = 0; i < 2; i++) {
        int c = tid + 256 * i;
        int r = c >> 3, kc = (c & 7) * 8;
        *(short8_t*)(As + r * LDT + kc) =
            *(const short8_t*)(Ab + (size_t)(row0 + r) * 256 + k0 + kc);
      }
    }
    __syncthreads();
#pragma unroll
    for (int kk = 0; kk < 64; kk += 32) {
      const int kof = kk + (lane >> 4) * 8;
      bf16x8_t af[4], bfr[4];
#pragma unroll
      for (int i = 0; i < 4; i++) {
        af[i] = __builtin_bit_cast(bf16x8_t,
            *(const short8_t*)(As + (i * 16 + (lane & 15)) * LDT + kof));
        bfr[i] = __builtin_bit_cast(bf16x8_t,
            *(const short8_t*)(Bs + (wn + i * 16 + (lane & 15)) * LDT + kof));
      }
#pragma unroll
      for (int i = 0; i < 4; i++)
#pragma unroll
        for (int j = 0; j < 4; j++)
          acc[i][j] = __builtin_amdgcn_mfma_f32_16x16x32_bf16(
              af[i], bfr[j], acc[i][j], 0, 0, 0);
    }
    __syncthreads();
  }
#pragma unroll
  for (int i = 0; i < 4; i++) {
    int row = row0 + i * 16 + ((lane >> 4) * 4);
#pragma unroll
    for (int j = 0; j < 4; j++) {
      int col = wn + j * 16 + (lane & 15);
      float bv = bias ? bias[col] * bias_scale : 0.f;
#pragma unroll
      for (int r = 0; r < 4; r++) {
        float v = acc[i][j][r] + bv;
        size_t off = (size_t)(row + r) * c_stride + c_coloff + col;
        if (Cf) Cf[off] = v;
        else Cb[off] = f2bf(v);
      }
    }
  }
}

// ---------- top-k body: SUBL lanes per cell-sorted a-point ----------
__device__ __forceinline__ void topk_body(
    int vbid, const unsigned* __restrict__ boff, const uint2* __restrict__ bcj,
    const uint2* __restrict__ acj, int* __restrict__ idxb,
    float* __restrict__ dwb, unsigned* __restrict__ failcnt,
    unsigned* __restrict__ faillist) {
  const int tid = vbid * 256 + threadIdx.x;
  const int t = tid / SUBL;        // cell-sorted a index
  const int sub = tid & (SUBL - 1);
  const uint2 av = acj[t];
  const int batch = t >> 13;  // batches are contiguous in cell order
  const int ax = av.x & 127, ay = (av.x >> 7) & 127, az = (av.x >> 14) & 127;
  const int cx = ax >> 4, cy = ay >> 4, cz = az >> 4;
  const int xlo = max(cx - 1, 0), xhi = min(cx + 1, 7);
  const int ylo = max(cy - 1, 0), yhi = min(cy + 1, 7);
  const int zlo = max(cz - 1, 0), zhi1 = min(cz + 1, 7) + 1;
  unsigned k[8];
#pragma unroll
  for (int s = 0; s < 8; s++) k[s] = 0xFFFFFFF8u + s;
  for (int nx = xlo; nx <= xhi; nx++) {
    for (int ny = ylo; ny <= yhi; ny++) {
      const int cb = (batch << 9) | (nx << 6) | (ny << 3);
      const int gs = (int)boff[cb + zlo];
      const int ge = (int)boff[cb + zhi1];
      for (int i = gs + sub; i < ge; i += SUBL) {
        const uint2 b = bcj[i];
        const int dx = ax - (int)(b.x & 127);
        const int dy = ay - (int)((b.x >> 7) & 127);
        const int dz = az - (int)((b.x >> 14) & 127);
        const unsigned d2 = (unsigned)(__mul24(dx, dx) + __mul24(dy, dy) +
                                       __mul24(dz, dz));
        kins(k, (d2 << 13) | b.y);
      }
    }
  }
  const int lane = threadIdx.x & 63;
#pragma unroll
  for (int half = 1; half < SUBL; half <<= 1) {
    unsigned o[8];
#pragma unroll
    for (int s = 0; s < 8; s++)
      o[s] = (unsigned)__shfl((int)k[s], lane ^ half, 64);
#pragma unroll
    for (int s = 0; s < 8; s++) kins(k, o[s]);
  }
  if (sub == 0) {
    const int g = (batch << 13) | (int)av.y;
#pragma unroll
    for (int s = 0; s < 8; s++) {
      unsigned key = k[s];
      idxb[(size_t)g * 8 + s] = (int)(key & 8191u);
      float dist = sqrtf((float)(key >> 13)) * (1.0f / 128.0f);
      dwb[(size_t)g * 8 + s] = 0.5f - fminf(dist, 0.5f);
    }
    if (k[7] >= (289u << 13)) {
      unsigned fp = atomicAdd(failcnt, 1u);
      faillist[fp] = (unsigned)g;
    }
  }
}

// ---------- merged launch: gemm_ab (blocks [0,1024)) + topk_bins ([1024,2048)) ----------
// The two halves have NO mutual dependency (gemm needs prep_weights; topk
// needs the binning chain). Serially they ran 53us + topk; merged, the CU
// scheduler fills the gemm's barrier/vmcnt idle bubbles (MfmaUtil 5.6%,
// VALUBusy 8%, Occ 20% -- mostly idle) with topk's VALU-heavy kins chains.
// Cost: topk blocks inherit the 46KB LDS reservation (3 blocks/CU), kept
// acceptable by the co-resident gemm waves providing the latency hiding.
__global__ __launch_bounds__(256, 3) void gemm_topk(
    const float* __restrict__ a_feats, const float* __restrict__ b_feats,
    const short* __restrict__ Wb16, const short* __restrict__ Wdiff,
    unsigned short* __restrict__ Pa, unsigned short* __restrict__ Pb,
    const float* __restrict__ b1, float* __restrict__ outp,
    const unsigned* __restrict__ boff, const uint2* __restrict__ bcj,
    const uint2* __restrict__ acj, int* __restrict__ idxb,
    float* __restrict__ dwb, unsigned* __restrict__ failcnt,
    unsigned* __restrict__ faillist) {
  __shared__ __attribute__((aligned(16))) short As[64 * LDT];
  __shared__ __attribute__((aligned(16))) short Bs[256 * LDT];
  const int nb = NPTS / 64;  // 512
  if (blockIdx.x < 2 * nb) {
    const int isB = blockIdx.x >= nb;
    const int rowblk = isB ? (blockIdx.x - nb) : blockIdx.x;
    const float* Af = isB ? b_feats : a_feats;
    const short* W = isB ? Wdiff : Wb16;
    unsigned short* P = isB ? Pb : Pa;
    const float* bias = isB ? nullptr : b1;
    float* copy = isB ? nullptr : outp;
    gemm64_body<1>(rowblk, (const void*)Af, W, nullptr, P, bias, 1.0f, 256, 0,
                   copy, As, Bs);
  } else {
    topk_body(blockIdx.x - 2 * nb, boff, bcj, acj, idxb, dwb, failcnt,
              faillist);
  }
}

// Final: out[:, :, 256:512] = H @ w2^T + 8*b2
__global__ __launch_bounds__(256, 3) void gemm_h(
    const short* __restrict__ Hb, const short* __restrict__ W2b,
    float* __restrict__ outp, const float* __restrict__ b2) {
  __shared__ __attribute__((aligned(16))) short As[64 * LDT];
  __shared__ __attribute__((aligned(16))) short Bs[256 * LDT];
  gemm64_body<0>(blockIdx.x, (const void*)Hb, W2b, outp, nullptr, b2, 8.0f,
                 512, 256, nullptr, As, Bs);
}

// ---------- fallback: exact full scan, one BLOCK (256 threads) per failed a-point ----------
__global__ __launch_bounds__(256) void topk_fallback(
    const unsigned* __restrict__ failcnt, const unsigned* __restrict__ faillist,
    const uint2* __restrict__ bcj, const unsigned* __restrict__ apk,
    int* __restrict__ idxb, float* __restrict__ dwb) {
  __shared__ unsigned sk[4 * 8];
  const int tid = threadIdx.x;
  const int wv = tid >> 6, lane = tid & 63;
  const unsigned nf = *failcnt;
  for (unsigned fi = blockIdx.x; fi < nf; fi += gridDim.x) {
    const unsigned g = faillist[fi];
    const int batch = (int)(g >> 13);
    const unsigned av = apk[g];
    const int ax = av & 127, ay = (av >> 7) & 127, az = (av >> 14) & 127;
    const uint2* pb = bcj + ((size_t)batch << 13);
    unsigned k[8];
#pragma unroll
    for (int s = 0; s < 8; s++) k[s] = 0xFFFFFFF8u + s;
#pragma unroll 8
    for (int i = tid; i < NB; i += 256) {
      const uint2 b = pb[i];
      const int dx = ax - (int)(b.x & 127);
      const int dy = ay - (int)((b.x >> 7) & 127);
      const int dz = az - (int)((b.x >> 14) & 127);
      const unsigned d2 = (unsigned)(__mul24(dx, dx) + __mul24(dy, dy) +
                                     __mul24(dz, dz));
      kins(k, (d2 << 13) | b.y);
    }
#pragma unroll
    for (int half = 32; half >= 1; half >>= 1) {
      unsigned o[8];
#pragma unroll
      for (int s = 0; s < 8; s++)
        o[s] = (unsigned)__shfl((int)k[s], lane ^ half, 64);
#pragma unroll
      for (int s = 0; s < 8; s++) kins(k, o[s]);
    }
    if (lane == 0) {
#pragma unroll
      for (int s = 0; s < 8; s++) sk[wv * 8 + s] = k[s];
    }
    __syncthreads();
    if (tid == 0) {
#pragma unroll
      for (int w = 1; w < 4; w++)
#pragma unroll
        for (int s = 0; s < 8; s++) kins(k, sk[w * 8 + s]);
#pragma unroll
      for (int s = 0; s < 8; s++) {
        unsigned key = k[s];
        idxb[(size_t)g * 8 + s] = (int)(key & 8191u);
        float dist = sqrtf((float)(key >> 13)) * (1.0f / 128.0f);
        dwb[(size_t)g * 8 + s] = 0.5f - fminf(dist, 0.5f);
      }
    }
    __syncthreads();  // sk reused next fi iteration
  }
}

// ---------- fuse: hsum = sum_k relu(Pa + Pb[idx_k]) * dw_k ----------
// Processes a-points in CELL-SORTED order (via acj): adjacent waves handle
// spatially adjacent a-points whose 8-neighbor sets overlap heavily, so the
// gathered Pb rows hit L1/L2 instead of HBM.
__global__ __launch_bounds__(256) void fuse_kernel(
    const unsigned short* __restrict__ Pa, const unsigned short* __restrict__ Pb,
    const uint2* __restrict__ acj, const int* __restrict__ idxb,
    const float* __restrict__ dwb, unsigned short* __restrict__ H) {
  const int t = blockIdx.x * 4 + (threadIdx.x >> 6);  // cell-sorted index
  const int lane = threadIdx.x & 63;
  const int batch = t >> 13;
  const uint2 av = acj[t];
  const int g = (batch << 13) | (int)av.y;
  const size_t fo = (size_t)g * 256 + lane * 4;
  ushort4 pav = *(const ushort4*)(Pa + fo);
  const float pa0 = bf2f(pav.x), pa1 = bf2f(pav.y), pa2 = bf2f(pav.z),
              pa3 = bf2f(pav.w);
  float h0 = 0.f, h1 = 0.f, h2 = 0.f, h3 = 0.f;
  const size_t bbase = (size_t)(batch << 13) * 256;
#pragma unroll
  for (int k = 0; k < 8; k++) {
    const int j = idxb[(size_t)g * 8 + k];
    const float w = dwb[(size_t)g * 8 + k];
    const ushort4 pbv =
        *(const ushort4*)(Pb + bbase + (size_t)j * 256 + lane * 4);
    h0 += fmaxf(pa0 + bf2f(pbv.x), 0.f) * w;
    h1 += fmaxf(pa1 + bf2f(pbv.y), 0.f) * w;
    h2 += fmaxf(pa2 + bf2f(pbv.z), 0.f) * w;
    h3 += fmaxf(pa3 + bf2f(pbv.w), 0.f) * w;
  }
  ushort4 hv;
  hv.x = f2bf(h0); hv.y = f2bf(h1); hv.z = f2bf(h2); hv.w = f2bf(h3);
  *(ushort4*)(H + fo) = hv;
}

// ---------- launch ----------
extern "C" void kernel_launch(void* const* d_in, const int* in_sizes, int n_in,
                              void* d_out, int out_size, void* d_ws,
                              size_t ws_size, hipStream_t stream) {
  const float* a_feats = (const float*)d_in[0];
  const float* b_feats = (const float*)d_in[1];
  const int* coords_a = (const int*)d_in[2];
  const int* coords_b = (const int*)d_in[3];
  const float* w1 = (const float*)d_in[4];
  const float* b1 = (const float*)d_in[5];
  const float* w2 = (const float*)d_in[6];
  const float* b2 = (const float*)d_in[7];
  float* outp = (float*)d_out;

  char* p = (char*)d_ws;
  auto take = [&](size_t bytes) {
    char* r = p;
    p += (bytes + 255) & ~(size_t)255;
    return r;
  };
  unsigned short* Pa = (unsigned short*)take((size_t)NPTS * DIM * 2);
  unsigned short* Pb = (unsigned short*)take((size_t)NPTS * DIM * 2);
  unsigned short* Hb = (unsigned short*)take((size_t)NPTS * DIM * 2);
  int* idxb = (int*)take((size_t)NPTS * 8 * 4);
  float* dwb = (float*)take((size_t)NPTS * 8 * 4);
  unsigned* bpk = (unsigned*)take((size_t)NPTS * 4);
  unsigned* apk = (unsigned*)take((size_t)NPTS * 4);
  unsigned* bcnt = (unsigned*)take(NCELL * 4);
  unsigned* acnt = (unsigned*)take(NCELL * 4);
  unsigned* bcur = (unsigned*)take(NCELL * 4);
  unsigned* acur = (unsigned*)take(NCELL * 4);
  unsigned* boff = (unsigned*)take((NCELL + 1) * 4);
  unsigned* aoff = (unsigned*)take((NCELL + 1) * 4);
  uint2* bcj = (uint2*)take((size_t)NPTS * 8);
  uint2* acj = (uint2*)take((size_t)NPTS * 8);
  unsigned* failcnt = (unsigned*)take(256);
  unsigned* faillist = (unsigned*)take((size_t)NPTS * 4);
  unsigned short* Wdiff = (unsigned short*)take((size_t)4 * WSLAB * 2);
  unsigned short* Wb16 = (unsigned short*)take((size_t)4 * WSLAB * 2);
  unsigned short* W2b = (unsigned short*)take((size_t)4 * WSLAB * 2);

  prep_weights<<<256, 256, 0, stream>>>(w1, w2, Wdiff, Wb16, W2b, bcnt, acnt,
                                        failcnt);
  pack_count_ab<<<2 * NPTS / 256, 256, 0, stream>>>(coords_b, coords_a, bpk,
                                                    apk, bcnt, acnt);
  scan_cells<<<1, 256, 0, stream>>>(bcnt, acnt, boff, aoff, bcur, acur);
  scatter_ab<<<2 * NPTS / 256, 256, 0, stream>>>(bpk, apk, bcur, acur, bcj,
                                                 acj);

  // gemm_ab (blocks [0,1024)) + topk_bins ([1024,2048)) in ONE launch:
  // independent work co-scheduled so topk fills the gemm's idle bubbles.
  gemm_topk<<<2 * NPTS / 64 + NPTS * SUBL / 256, 256, 0, stream>>>(
      a_feats, b_feats, (const short*)Wb16, (const short*)Wdiff, Pa, Pb, b1,
      outp, boff, bcj, acj, idxb, dwb, failcnt, faillist);

  topk_fallback<<<256, 256, 0, stream>>>(failcnt, faillist, bcj, apk, idxb,
                                         dwb);

  fuse_kernel<<<NPTS / 4, 256, 0, stream>>>(Pa, Pb, acj, idxb, dwb, Hb);

  // out[:, :, 256:512] = H @ w2^T + 8*b2
  gemm_h<<<NPTS / 64, 256, 0, stream>>>((const short*)Hb, (const short*)W2b,
                                        outp, b2);
}